// Round 10
// baseline (347.137 us; speedup 1.0000x reference)
//
#include <hip/hip_runtime.h>
#include <stdint.h>

typedef unsigned short u16;
typedef __attribute__((ext_vector_type(4))) float f32x4;
typedef __attribute__((ext_vector_type(8))) short bf16x8;
typedef __attribute__((ext_vector_type(4))) uint32_t u32x4;

#define D_MODEL 2048
#define NHEADS 16
#define HD 128
#define BSZ 2
#define TQ 1024
#define XL 1024
#define KVLEN 2048

__device__ __forceinline__ float b2f(u16 u) {
  union { uint32_t i; float f; } x; x.i = ((uint32_t)u) << 16; return x.f;
}
__device__ __forceinline__ u16 f2b(float f) {
  union { float f; uint32_t i; } x; x.f = f;
  uint32_t r = x.i + 0x7FFFu + ((x.i >> 16) & 1u);  // RNE
  return (u16)(r >> 16);
}

union U4 { u32x4 u; u16 s[8]; };

__device__ __forceinline__ void async_copy16(const u16* g, u16* l) {
  __builtin_amdgcn_global_load_lds((__attribute__((address_space(1))) void*)g,
                                   (__attribute__((address_space(3))) void*)l,
                                   16, 0, 0);
}

struct PrefF32 {  // 8 fp32 -> 8 bf16 pack
  f32x4 lo, hi;
  __device__ __forceinline__ void load(const float* base, size_t off) {
    lo = *(const f32x4*)(base + off);
    hi = *(const f32x4*)(base + off + 4);
  }
  __device__ __forceinline__ u32x4 pack() const {
    U4 o;
    o.s[0] = f2b(lo[0]); o.s[1] = f2b(lo[1]); o.s[2] = f2b(lo[2]); o.s[3] = f2b(lo[3]);
    o.s[4] = f2b(hi[0]); o.s[5] = f2b(hi[1]); o.s[6] = f2b(hi[2]); o.s[7] = f2b(hi[3]);
    return o.u;
  }
};

// ---------------------------------------------------------------------------
// fp32 -> bf16 elementwise, 8 elems/thread
// ---------------------------------------------------------------------------
__global__ __launch_bounds__(256, 4) void cvt_bf16(
    const float* __restrict__ src, u16* __restrict__ dst)
{
  const size_t id = (size_t)blockIdx.x * 256 + threadIdx.x;
  PrefF32 p; p.load(src, id * 8);
  *(u32x4*)&dst[id * 8] = p.pack();
}

// ---------------------------------------------------------------------------
// C = A * Bt^T, all-bf16 m97 structure: 128xBN tile, BK=32, 256 thr (2x2
// waves), 16x16x32 MFMA, async global_load_lds width=16 both operands.
// BN = 128 (gemm1) or 64 (gemm2: 2x blocks for the small-N shape).
// CSPLIT: C bf16 routed to one of 3 buffers (stride 2048); else C fp32.
// ---------------------------------------------------------------------------
template <int BN, bool CSPLIT>
__global__ __launch_bounds__(256, 2) void gemm_bt(
    const u16* __restrict__ A, const u16* __restrict__ B,
    void* __restrict__ C0, void* __restrict__ C1, void* __restrict__ C2,
    int M, int N, int K)
{
  constexpr int JN = BN / 32;  // n-frags per wave
  __shared__ u16 sA[128 * 32];
  __shared__ u16 sB[BN * 32];
  const int tid  = threadIdx.x;
  const int lane = tid & 63;
  const int wave = tid >> 6;
  const int quad = lane >> 4;
  const int mcol = lane & 15;
  const int wm = (wave >> 1) * 64;
  const int wn = (wave & 1) * (BN / 2);
  const int bm = blockIdx.y * 128;
  const int bnE = blockIdx.x * BN;

  f32x4 acc[4][JN] = {};

  // chunk c (8 elems, 16B) at LDS c*8: row = c>>2, kq = (c&3)*8
  const int c0 = tid, c1 = tid + 256;
  size_t a0 = (size_t)(bm + (c0 >> 2)) * K + (c0 & 3) * 8;
  size_t a1 = (size_t)(bm + (c1 >> 2)) * K + (c1 & 3) * 8;
  size_t b0 = (size_t)(bnE + (c0 >> 2)) * K + (c0 & 3) * 8;
  size_t b1 = (BN == 128) ? (size_t)(bnE + (c1 >> 2)) * K + (c1 & 3) * 8 : 0;

  const int nk = K >> 5;
  for (int kk = 0; kk < nk; ++kk) {
    async_copy16(A + a0, &sA[c0 * 8]);
    async_copy16(A + a1, &sA[c1 * 8]);
    async_copy16(B + b0, &sB[c0 * 8]);
    if (BN == 128) async_copy16(B + b1, &sB[c1 * 8]);
    a0 += 32; a1 += 32; b0 += 32; b1 += 32;
    __syncthreads();  // drains vmcnt (global_load_lds) before frag reads
    bf16x8 af[4], bff[JN];
#pragma unroll
    for (int i = 0; i < 4; ++i)
      af[i] = *(const bf16x8*)&sA[(wm + i * 16 + mcol) * 32 + quad * 8];
#pragma unroll
    for (int j = 0; j < JN; ++j)
      bff[j] = *(const bf16x8*)&sB[(wn + j * 16 + mcol) * 32 + quad * 8];
#pragma unroll
    for (int i = 0; i < 4; ++i)
#pragma unroll
      for (int j = 0; j < JN; ++j)
        acc[i][j] = __builtin_amdgcn_mfma_f32_16x16x32_bf16(af[i], bff[j], acc[i][j], 0, 0, 0);
    __syncthreads();  // frag reads done before next staging
  }

  // epilogue: C row = quad*4 + reg, col = mcol (m89-verified C/D layout)
  if (CSPLIT) {
    const int sel = bnE >> 11;
    u16* Cp = (u16*)(sel == 0 ? C0 : (sel == 1 ? C1 : C2));
    const int bnl = (bnE & 2047) + wn;
#pragma unroll
    for (int i = 0; i < 4; ++i)
#pragma unroll
      for (int r = 0; r < 4; ++r) {
        const size_t base = (size_t)(bm + wm + i * 16 + quad * 4 + r) * 2048 + bnl;
#pragma unroll
        for (int j = 0; j < JN; ++j)
          Cp[base + j * 16 + mcol] = f2b(acc[i][j][r]);
      }
  } else {
    float* Cp = (float*)C0;
#pragma unroll
    for (int i = 0; i < 4; ++i)
#pragma unroll
      for (int r = 0; r < 4; ++r) {
        const size_t base = (size_t)(bm + wm + i * 16 + quad * 4 + r) * N + bnE + wn;
#pragma unroll
        for (int j = 0; j < JN; ++j)
          Cp[base + j * 16 + mcol] = acc[i][j][r];
      }
  }
}

// ---------------------------------------------------------------------------
// kfull[b,h,kv,d]: kv<XL -> bf16(kxl + pos); kv>=XL -> rope(kbuf) with cos/sin.
// ---------------------------------------------------------------------------
__global__ __launch_bounds__(256, 4) void prep_k(
    const float* __restrict__ kxl, const float* __restrict__ pos,
    const u16* __restrict__ kbuf, const float* __restrict__ cosw,
    const float* __restrict__ sinw, u16* __restrict__ kfull)
{
  const int id = blockIdx.x * 256 + threadIdx.x;
  const int dc = id & 15;
  const int kv = (id >> 4) & 2047;
  const int bh = id >> 15;
  const int b = bh >> 4, h = bh & 15;
  const int d0 = dc * 8;
  U4 o;
  if (kv < XL) {
    const float* kp = kxl + ((size_t)b * XL + kv) * D_MODEL + h * HD + d0;
    const float* pp = pos + (size_t)kv * D_MODEL + h * HD + d0;
    f32x4 kl = *(const f32x4*)kp, kh = *(const f32x4*)(kp + 4);
    f32x4 pl = *(const f32x4*)pp, ph = *(const f32x4*)(pp + 4);
#pragma unroll
    for (int p = 0; p < 4; ++p) {
      o.s[p]     = f2b(kl[p] + pl[p]);
      o.s[4 + p] = f2b(kh[p] + ph[p]);
    }
  } else {
    const int tq = kv - XL;
    U4 kv_;
    kv_.u = *(const u32x4*)(kbuf + ((size_t)b * TQ + tq) * D_MODEL + h * HD + d0);
    f32x4 cv = *(const f32x4*)(cosw + tq * 64 + (d0 >> 1));
    f32x4 sv = *(const f32x4*)(sinw + tq * 64 + (d0 >> 1));
#pragma unroll
    for (int p = 0; p < 4; ++p) {
      const float e = b2f(kv_.s[2 * p]), od = b2f(kv_.s[2 * p + 1]);
      o.s[2 * p]     = f2b(e * cv[p] - od * sv[p]);
      o.s[2 * p + 1] = f2b(e * sv[p] + od * cv[p]);
    }
  }
  *(u32x4*)&kfull[((size_t)bh * KVLEN + kv) * HD + d0] = o.u;
}

// ---------------------------------------------------------------------------
// vt[b,h,d,kv] = (kv < XL) ? cvt(v_xl fp32) : vbuf bf16. 64x64 LDS transpose.
// ---------------------------------------------------------------------------
__global__ __launch_bounds__(256, 4) void transpose_v(
    const float* __restrict__ v_xl, const u16* __restrict__ vbuf, u16* __restrict__ vt)
{
  __shared__ u16 tile[64 * 72];
  const int tid = threadIdx.x;
  const int kv0 = blockIdx.x * 64;
  const int d0  = blockIdx.y * 64;
  const int bh  = blockIdx.z;
  const int b = bh >> 4, h = bh & 15;
#pragma unroll
  for (int j = 0; j < 2; ++j) {
    const int id = tid + 256 * j;
    const int kr = id >> 3, dq = (id & 7) * 8;
    const int kvg = kv0 + kr;
    if (kvg < XL) {
      const float* src = v_xl + ((size_t)b * XL + kvg) * D_MODEL + h * HD + d0 + dq;
      PrefF32 p; p.load(src, 0);
      *(u32x4*)&tile[kr * 72 + dq] = p.pack();
    } else {
      const u16* src = vbuf + ((size_t)b * TQ + (kvg - XL)) * D_MODEL + h * HD + d0 + dq;
      *(u32x4*)&tile[kr * 72 + dq] = *(const u32x4*)src;
    }
  }
  __syncthreads();
#pragma unroll
  for (int j = 0; j < 2; ++j) {
    const int id = tid + 256 * j;
    const int dr = id >> 3, kq = (id & 7) * 8;
    U4 ov;
#pragma unroll
    for (int i = 0; i < 8; ++i) ov.s[i] = tile[(kq + i) * 72 + dr];
    *(u32x4*)&vt[((size_t)bh * HD + d0 + dr) * KVLEN + kv0 + kq] = ov.u;
  }
}

// ---------------------------------------------------------------------------
// Flash attention v10 = v9 (swapped QK^T + in-reg P + deswizzle) with
// KVBLK 128 -> 64. Rationale (v1/v8/v9 post-mortem): attn dur invariant at
// ~90us across traffic/shuffle/barrier changes -> bound by per-tile serial
// chain x only 2 co-resident blocks/CU (LDS 69.6KB). Halving the kv tile:
//   sK 64x136 + sV 128x72 = 35.8KB -> 4 blocks/CU (143/160KB);
//   kreg/vreg/s arrays halve -> ~75-90 VGPR -> 16 waves/CU at (256,2)
//   (no round-4 spill trap: bound stays at min-2-blocks, usage just drops).
// 4 independent block pipelines per CU cover each other's barrier drains
// (previously only 1 partner). Tiles double to 32; chain per tile halves.
// ---------------------------------------------------------------------------
#define LSTR 136  // sK: d-stride = 128 + 8 pad (16B-aligned chunks)
#define VSTR 72   // sV: kv-stride = 64 + 8 pad

__global__ __launch_bounds__(256, 2) void attn(
    const u16* __restrict__ q, const u16* __restrict__ kfull,
    const u16* __restrict__ vt, const float* __restrict__ cosw,
    const float* __restrict__ sinw, const int* __restrict__ iscausal,
    u16* __restrict__ y)
{
  __shared__ u16 sK[64 * LSTR];   // K tile [kv][d]
  __shared__ u16 sV[128 * VSTR];  // V^T tile [d][kv]

  const int tid  = threadIdx.x;
  const int lane = tid & 63;
  const int w    = tid >> 6;
  const int quad = lane >> 4;
  const int mcol = lane & 15;
  // deswizzle: lin%8 = XCD. qt in bits [6:3] -> all qt of a bh share XCD.
  const int lin = blockIdx.x + 16 * blockIdx.y;  // 0..511
  const int qt  = (lin >> 3) & 15;
  const int bh  = (lin & 7) + 8 * (lin >> 7);
  const int b = bh >> 4, h = bh & 15;
  const int causal = *iscausal;
  const float SC = 0.08838834764831845f;  // 1/sqrt(128)

  // ---- Q fragments with fused rope, pre-scaled by SC (B-operand of
  // s = mfma(K, Q): lane holds Q[q=mcol][d=ks*32+quad*8+j]).
  bf16x8 qf[4];
  {
    const int trow = qt * 64 + w * 16 + mcol;
    const u16* qrow = q + ((size_t)b * TQ + trow) * D_MODEL + h * HD;
    const float* crow = cosw + trow * 64;
    const float* srow = sinw + trow * 64;
#pragma unroll
    for (int ks = 0; ks < 4; ++ks) {
      const int d0 = ks * 32 + quad * 8;
      U4 qv; qv.u = *(const u32x4*)(qrow + d0);
      f32x4 cv = *(const f32x4*)(crow + (d0 >> 1));
      f32x4 sv = *(const f32x4*)(srow + (d0 >> 1));
      bf16x8 dst;
#pragma unroll
      for (int p = 0; p < 4; ++p) {
        const float e = b2f(qv.s[2 * p]), o = b2f(qv.s[2 * p + 1]);
        const float re = fmaf(-o, sv[p], e * cv[p]);  // single-rounding combine
        const float im = fmaf( o, cv[p], e * sv[p]);
        dst[2 * p]     = (short)f2b(re * SC);
        dst[2 * p + 1] = (short)f2b(im * SC);
      }
      qf[ks] = dst;
    }
  }

  // staging coords:
  //   K: row rr = (tid>>4)+16j (0..63), elems sc8 = (tid&15)*8 of 128
  //   V: row dr = (tid>>3)+32j (0..127), elems vc8 = (tid&7)*8 of 64
  const int srow = tid >> 4;
  const int sc8  = (tid & 15) * 8;
  const int vrow_t = tid >> 3;
  const int vc8  = (tid & 7) * 8;
  const u16* kbase = kfull + (size_t)bh * KVLEN * HD;
  const u16* vbase = vt + (size_t)bh * HD * KVLEN;

  u32x4 kreg[4], vreg[4];
#define LOADT(KV0)                                                           \
  do {                                                                       \
    _Pragma("unroll") for (int j = 0; j < 4; ++j) {                          \
      const int rr = srow + 16 * j;                                          \
      const int dr = vrow_t + 32 * j;                                        \
      kreg[j] = *(const u32x4*)(kbase + ((size_t)(KV0) + rr) * HD + sc8);    \
      vreg[j] = *(const u32x4*)(vbase + (size_t)dr * KVLEN + (KV0) + vc8);   \
    }                                                                        \
  } while (0)

  f32x4 oacc[8] = {};          // O[q=quad*4+r][d=nd*16+mcol] (C layout)
  float mrun = -3.0e38f;       // running max for q = mcol
  float lrun = 0.f;            // running denom for q = mcol

  LOADT(0);
  for (int t = 0; t < 32; ++t) {
    __syncthreads();  // previous iteration's LDS reads done before restaging
#pragma unroll
    for (int j = 0; j < 4; ++j) {
      const int rr = srow + 16 * j;
      const int dr = vrow_t + 32 * j;
      *(u32x4*)&sK[rr * LSTR + sc8] = kreg[j];
      *(u32x4*)&sV[dr * VSTR + vc8] = vreg[j];
    }
    __syncthreads();  // staging visible
    if (t < 31) LOADT((t + 1) * 64);  // prefetch next tile (hides latency)

    const int kv0 = t * 64;

    // ---- S^T = K Q^T: s[nt][r] = S[q=mcol][kv = kv0 + nt*16 + quad*4 + r]
    f32x4 s[4] = {};
#pragma unroll
    for (int ks = 0; ks < 4; ++ks) {
      const int cc = ks * 4 + quad;
#pragma unroll
      for (int nt = 0; nt < 4; ++nt) {
        bf16x8 kf = *(const bf16x8*)&sK[(nt * 16 + mcol) * LSTR + cc * 8];
        s[nt] = __builtin_amdgcn_mfma_f32_16x16x32_bf16(kf, qf[ks], s[nt], 0, 0, 0);
      }
    }
    if (causal) {
      const int qi = qt * 64 + w * 16 + mcol;
#pragma unroll
      for (int nt = 0; nt < 4; ++nt)
#pragma unroll
        for (int r = 0; r < 4; ++r) {
          const int ki = kv0 + nt * 16 + quad * 4 + r;
          if (ki > qi + (KVLEN - TQ)) s[nt][r] = -1.0e30f;
        }
    }

    // ---- online softmax for q = mcol: in-lane over 16 + 2 shfl_xor
    float tm = -3.0e38f;
#pragma unroll
    for (int nt = 0; nt < 4; ++nt) {
      const float t01 = fmaxf(s[nt][0], s[nt][1]);
      const float t23 = fmaxf(s[nt][2], s[nt][3]);
      tm = fmaxf(tm, fmaxf(t01, t23));
    }
    tm = fmaxf(tm, __shfl_xor(tm, 16));
    tm = fmaxf(tm, __shfl_xor(tm, 32));
    const float mo = mrun;
    const float mn = fmaxf(mo, tm);
    mrun = mn;
    const float al = __expf(mo - mn);
    float rs = 0.f;
#pragma unroll
    for (int nt = 0; nt < 4; ++nt)
#pragma unroll
      for (int r = 0; r < 4; ++r) {
        const float p = __expf(s[nt][r] - mn);
        s[nt][r] = p;
        rs += p;
      }
    rs += __shfl_xor(rs, 16);
    rs += __shfl_xor(rs, 32);
    lrun = lrun * al + rs;

    // alpha for O rows: O row q = quad*4+r lives at source lane mcol=quad*4+r
    float al4[4];
#pragma unroll
    for (int r = 0; r < 4; ++r)
      al4[r] = __shfl(al, (lane & 48) + quad * 4 + r);
#pragma unroll
    for (int nd = 0; nd < 8; ++nd)
#pragma unroll
      for (int r = 0; r < 4; ++r) oacc[nd][r] *= al4[r];

    // ---- O += P V, P fully in registers (kv slot permutation as v9,
    // ks now 0..1 over 64 kv). B-frag: two b64 reads per fragment.
#pragma unroll
    for (int ks = 0; ks < 2; ++ks) {
      U4 pa;
#pragma unroll
      for (int e = 0; e < 4; ++e) {
        pa.s[e]     = f2b(s[2 * ks][e]);
        pa.s[4 + e] = f2b(s[2 * ks + 1][e]);
      }
      const int kvlo = 32 * ks + 4 * quad;
#pragma unroll
      for (int nd = 0; nd < 8; ++nd) {
        const u16* vrow = &sV[(nd * 16 + mcol) * VSTR + kvlo];
        U4 vf;
        *(uint2*)&vf.s[0] = *(const uint2*)(vrow);
        *(uint2*)&vf.s[4] = *(const uint2*)(vrow + 16);
        oacc[nd] = __builtin_amdgcn_mfma_f32_16x16x32_bf16(
            *(const bf16x8*)&pa, *(const bf16x8*)&vf, oacc[nd], 0, 0, 0);
      }
    }
  }
#undef LOADT

  // ---- epilogue: y[b, t, h*HD + d] = O / l (bf16); l crosses lanes like al
  float lq[4];
#pragma unroll
  for (int r = 0; r < 4; ++r)
    lq[r] = __shfl(lrun, (lane & 48) + quad * 4 + r);
#pragma unroll
  for (int r = 0; r < 4; ++r) {
    const int trow = qt * 64 + w * 16 + quad * 4 + r;
    const float inv = 1.0f / lq[r];
    u16* yr = y + ((size_t)b * TQ + trow) * D_MODEL + h * HD;
#pragma unroll
    for (int nd = 0; nd < 8; ++nd)
      yr[nd * 16 + mcol] = f2b(oacc[nd][r] * inv);
  }
}

// ---------------------------------------------------------------------------
extern "C" void kernel_launch(void* const* d_in, const int* in_sizes, int n_in,
                              void* d_out, int out_size, void* d_ws, size_t ws_size,
                              hipStream_t stream) {
  const float* x      = (const float*)d_in[0];
  const float* cosw   = (const float*)d_in[1];
  const float* sinw   = (const float*)d_in[2];
  const float* k_xl   = (const float*)d_in[3];
  const float* v_xl   = (const float*)d_in[4];
  const float* pos    = (const float*)d_in[5];
  const float* w_qkv  = (const float*)d_in[6];
  const float* w_proj = (const float*)d_in[7];
  const int* isc      = (const int*)d_in[8];
  float* out = (float*)d_out;

  // ws layout (58.7 MB, overlap-safe by stream order):
  //   qbuf  @ 0          8.4M  (gemm1 out, attn in)
  //   kbuf  @ 8388608    8.4M  (gemm1 out, prep_k in) -> y_ws after prep_k
  //   vbuf  @ 16777216   8.4M  (gemm1 out, transpose_v in)
  //   wqb   @ 25165824  25.2M  (cvt out, gemm1 in; dead after gemm1)
  //   kfull @ 25165824  16.8M  (prep_k out, attn in; overlays dead wqb)
  //   wpb   @ 25165824   8.4M  (cvt AFTER attn; overlays dead kfull)
  //   vt    @ 41943040  16.8M  (transpose_v out after gemm1; overlays wqb tail)
  //   xb    @ 50331648   8.4M  (cvt out, gemm1 in; overwritten by vt tail later)
  char* ws = (char*)d_ws;
  u16* qbuf  = (u16*)ws;
  u16* kbuf  = (u16*)(ws + (size_t)8388608);
  u16* vbuf  = (u16*)(ws + (size_t)16777216);
  u16* wqb   = (u16*)(ws + (size_t)25165824);
  u16* kfull = (u16*)(ws + (size_t)25165824);
  u16* wpb   = (u16*)(ws + (size_t)25165824);
  u16* vt    = (u16*)(ws + (size_t)41943040);
  u16* xb    = (u16*)(ws + (size_t)50331648);
  u16* y_ws  = kbuf;

  // 1) x fp32 -> bf16 (4,194,304 elems)
  cvt_bf16<<<2048, 256, 0, stream>>>(x, xb);
  // 2) w_qkv fp32 -> bf16 (12,582,912 elems)
  cvt_bf16<<<6144, 256, 0, stream>>>(w_qkv, wqb);

  // 3) q/k/v = x @ w_qkv^T  (all-bf16 async, C split bf16)
  dim3 g1(48, 16);
  gemm_bt<128, true><<<g1, 256, 0, stream>>>(xb, wqb, qbuf, kbuf, vbuf, 2048, 6144, 2048);

  // 4) kfull[b,h,kv,d]
  prep_k<<<4096, 256, 0, stream>>>(k_xl, pos, kbuf, cosw, sinw, kfull);

  // 5) vt[b,h,d,kv]
  dim3 gt(KVLEN / 64, HD / 64, BSZ * NHEADS);
  transpose_v<<<gt, 256, 0, stream>>>(v_xl, vbuf, vt);

  // 6) flash attention -> y bf16 (b,t,c); XCD-deswizzled block mapping
  dim3 ga(16, BSZ * NHEADS);
  attn<<<ga, 256, 0, stream>>>(qbuf, kfull, vt, cosw, sinw, isc, y_ws);

  // 7) w_proj fp32 -> bf16 (after attn: wpb overlays dead kfull)
  cvt_bf16<<<2048, 256, 0, stream>>>(w_proj, wpb);

  // 8) out = y @ w_proj^T  (all-bf16 async, 128x64 tiles -> 512 blocks, C fp32)
  dim3 g2(32, 16);
  gemm_bt<64, false><<<g2, 256, 0, stream>>>(y_ws, wpb, out, nullptr, nullptr, 2048, 2048, 2048);
}

// Round 13
// 344.728 us; speedup vs baseline: 1.0070x; 1.0070x over previous
//
#include <hip/hip_runtime.h>
#include <stdint.h>

typedef unsigned short u16;
typedef __attribute__((ext_vector_type(4))) float f32x4;
typedef __attribute__((ext_vector_type(8))) short bf16x8;
typedef __attribute__((ext_vector_type(4))) uint32_t u32x4;

#define D_MODEL 2048
#define NHEADS 16
#define HD 128
#define BSZ 2
#define TQ 1024
#define XL 1024
#define KVLEN 2048

__device__ __forceinline__ float b2f(u16 u) {
  union { uint32_t i; float f; } x; x.i = ((uint32_t)u) << 16; return x.f;
}
__device__ __forceinline__ u16 f2b(float f) {
  union { float f; uint32_t i; } x; x.f = f;
  uint32_t r = x.i + 0x7FFFu + ((x.i >> 16) & 1u);  // RNE
  return (u16)(r >> 16);
}

union U4 { u32x4 u; u16 s[8]; };

__device__ __forceinline__ void async_copy16(const u16* g, u16* l) {
  __builtin_amdgcn_global_load_lds((__attribute__((address_space(1))) void*)g,
                                   (__attribute__((address_space(3))) void*)l,
                                   16, 0, 0);
}

struct PrefF32 {  // 8 fp32 -> 8 bf16 pack
  f32x4 lo, hi;
  __device__ __forceinline__ void load(const float* base, size_t off) {
    lo = *(const f32x4*)(base + off);
    hi = *(const f32x4*)(base + off + 4);
  }
  __device__ __forceinline__ u32x4 pack() const {
    U4 o;
    o.s[0] = f2b(lo[0]); o.s[1] = f2b(lo[1]); o.s[2] = f2b(lo[2]); o.s[3] = f2b(lo[3]);
    o.s[4] = f2b(hi[0]); o.s[5] = f2b(hi[1]); o.s[6] = f2b(hi[2]); o.s[7] = f2b(hi[3]);
    return o.u;
  }
};

// ---------------------------------------------------------------------------
// fp32 -> bf16 elementwise, 8 elems/thread
// ---------------------------------------------------------------------------
__global__ __launch_bounds__(256, 4) void cvt_bf16(
    const float* __restrict__ src, u16* __restrict__ dst)
{
  const size_t id = (size_t)blockIdx.x * 256 + threadIdx.x;
  PrefF32 p; p.load(src, id * 8);
  *(u32x4*)&dst[id * 8] = p.pack();
}

// ---------------------------------------------------------------------------
// C = A * Bt^T, all-bf16 m97 structure: 128xBN tile, BK=32, 256 thr (2x2
// waves), 16x16x32 MFMA, async global_load_lds width=16 both operands.
// BN = 128 (gemm1) or 64 (gemm2: 2x blocks for the small-N shape).
// CSPLIT: C bf16 routed to one of 3 buffers (stride 2048); else C fp32.
// ---------------------------------------------------------------------------
template <int BN, bool CSPLIT>
__global__ __launch_bounds__(256, 2) void gemm_bt(
    const u16* __restrict__ A, const u16* __restrict__ B,
    void* __restrict__ C0, void* __restrict__ C1, void* __restrict__ C2,
    int M, int N, int K)
{
  constexpr int JN = BN / 32;  // n-frags per wave
  __shared__ u16 sA[128 * 32];
  __shared__ u16 sB[BN * 32];
  const int tid  = threadIdx.x;
  const int lane = tid & 63;
  const int wave = tid >> 6;
  const int quad = lane >> 4;
  const int mcol = lane & 15;
  const int wm = (wave >> 1) * 64;
  const int wn = (wave & 1) * (BN / 2);
  const int bm = blockIdx.y * 128;
  const int bnE = blockIdx.x * BN;

  f32x4 acc[4][JN] = {};

  // chunk c (8 elems, 16B) at LDS c*8: row = c>>2, kq = (c&3)*8
  const int c0 = tid, c1 = tid + 256;
  size_t a0 = (size_t)(bm + (c0 >> 2)) * K + (c0 & 3) * 8;
  size_t a1 = (size_t)(bm + (c1 >> 2)) * K + (c1 & 3) * 8;
  size_t b0 = (size_t)(bnE + (c0 >> 2)) * K + (c0 & 3) * 8;
  size_t b1 = (BN == 128) ? (size_t)(bnE + (c1 >> 2)) * K + (c1 & 3) * 8 : 0;

  const int nk = K >> 5;
  for (int kk = 0; kk < nk; ++kk) {
    async_copy16(A + a0, &sA[c0 * 8]);
    async_copy16(A + a1, &sA[c1 * 8]);
    async_copy16(B + b0, &sB[c0 * 8]);
    if (BN == 128) async_copy16(B + b1, &sB[c1 * 8]);
    a0 += 32; a1 += 32; b0 += 32; b1 += 32;
    __syncthreads();  // drains vmcnt (global_load_lds) before frag reads
    bf16x8 af[4], bff[JN];
#pragma unroll
    for (int i = 0; i < 4; ++i)
      af[i] = *(const bf16x8*)&sA[(wm + i * 16 + mcol) * 32 + quad * 8];
#pragma unroll
    for (int j = 0; j < JN; ++j)
      bff[j] = *(const bf16x8*)&sB[(wn + j * 16 + mcol) * 32 + quad * 8];
#pragma unroll
    for (int i = 0; i < 4; ++i)
#pragma unroll
      for (int j = 0; j < JN; ++j)
        acc[i][j] = __builtin_amdgcn_mfma_f32_16x16x32_bf16(af[i], bff[j], acc[i][j], 0, 0, 0);
    __syncthreads();  // frag reads done before next staging
  }

  // epilogue: C row = quad*4 + reg, col = mcol (m89-verified C/D layout)
  if (CSPLIT) {
    const int sel = bnE >> 11;
    u16* Cp = (u16*)(sel == 0 ? C0 : (sel == 1 ? C1 : C2));
    const int bnl = (bnE & 2047) + wn;
#pragma unroll
    for (int i = 0; i < 4; ++i)
#pragma unroll
      for (int r = 0; r < 4; ++r) {
        const size_t base = (size_t)(bm + wm + i * 16 + quad * 4 + r) * 2048 + bnl;
#pragma unroll
        for (int j = 0; j < JN; ++j)
          Cp[base + j * 16 + mcol] = f2b(acc[i][j][r]);
      }
  } else {
    float* Cp = (float*)C0;
#pragma unroll
    for (int i = 0; i < 4; ++i)
#pragma unroll
      for (int r = 0; r < 4; ++r) {
        const size_t base = (size_t)(bm + wm + i * 16 + quad * 4 + r) * N + bnE + wn;
#pragma unroll
        for (int j = 0; j < JN; ++j)
          Cp[base + j * 16 + mcol] = acc[i][j][r];
      }
  }
}

// ---------------------------------------------------------------------------
// kfull[b,h,kv,d]: kv<XL -> bf16(kxl + pos); kv>=XL -> rope(kbuf) with cos/sin.
// ---------------------------------------------------------------------------
__global__ __launch_bounds__(256, 4) void prep_k(
    const float* __restrict__ kxl, const float* __restrict__ pos,
    const u16* __restrict__ kbuf, const float* __restrict__ cosw,
    const float* __restrict__ sinw, u16* __restrict__ kfull)
{
  const int id = blockIdx.x * 256 + threadIdx.x;
  const int dc = id & 15;
  const int kv = (id >> 4) & 2047;
  const int bh = id >> 15;
  const int b = bh >> 4, h = bh & 15;
  const int d0 = dc * 8;
  U4 o;
  if (kv < XL) {
    const float* kp = kxl + ((size_t)b * XL + kv) * D_MODEL + h * HD + d0;
    const float* pp = pos + (size_t)kv * D_MODEL + h * HD + d0;
    f32x4 kl = *(const f32x4*)kp, kh = *(const f32x4*)(kp + 4);
    f32x4 pl = *(const f32x4*)pp, ph = *(const f32x4*)(pp + 4);
#pragma unroll
    for (int p = 0; p < 4; ++p) {
      o.s[p]     = f2b(kl[p] + pl[p]);
      o.s[4 + p] = f2b(kh[p] + ph[p]);
    }
  } else {
    const int tq = kv - XL;
    U4 kv_;
    kv_.u = *(const u32x4*)(kbuf + ((size_t)b * TQ + tq) * D_MODEL + h * HD + d0);
    f32x4 cv = *(const f32x4*)(cosw + tq * 64 + (d0 >> 1));
    f32x4 sv = *(const f32x4*)(sinw + tq * 64 + (d0 >> 1));
#pragma unroll
    for (int p = 0; p < 4; ++p) {
      const float e = b2f(kv_.s[2 * p]), od = b2f(kv_.s[2 * p + 1]);
      o.s[2 * p]     = f2b(e * cv[p] - od * sv[p]);
      o.s[2 * p + 1] = f2b(e * sv[p] + od * cv[p]);
    }
  }
  *(u32x4*)&kfull[((size_t)bh * KVLEN + kv) * HD + d0] = o.u;
}

// ---------------------------------------------------------------------------
// vt[b,h,d,kv] = (kv < XL) ? cvt(v_xl fp32) : vbuf bf16. 64x64 LDS transpose.
// ---------------------------------------------------------------------------
__global__ __launch_bounds__(256, 4) void transpose_v(
    const float* __restrict__ v_xl, const u16* __restrict__ vbuf, u16* __restrict__ vt)
{
  __shared__ u16 tile[64 * 72];
  const int tid = threadIdx.x;
  const int kv0 = blockIdx.x * 64;
  const int d0  = blockIdx.y * 64;
  const int bh  = blockIdx.z;
  const int b = bh >> 4, h = bh & 15;
#pragma unroll
  for (int j = 0; j < 2; ++j) {
    const int id = tid + 256 * j;
    const int kr = id >> 3, dq = (id & 7) * 8;
    const int kvg = kv0 + kr;
    if (kvg < XL) {
      const float* src = v_xl + ((size_t)b * XL + kvg) * D_MODEL + h * HD + d0 + dq;
      PrefF32 p; p.load(src, 0);
      *(u32x4*)&tile[kr * 72 + dq] = p.pack();
    } else {
      const u16* src = vbuf + ((size_t)b * TQ + (kvg - XL)) * D_MODEL + h * HD + d0 + dq;
      *(u32x4*)&tile[kr * 72 + dq] = *(const u32x4*)src;
    }
  }
  __syncthreads();
#pragma unroll
  for (int j = 0; j < 2; ++j) {
    const int id = tid + 256 * j;
    const int dr = id >> 3, kq = (id & 7) * 8;
    U4 ov;
#pragma unroll
    for (int i = 0; i < 8; ++i) ov.s[i] = tile[(kq + i) * 72 + dr];
    *(u32x4*)&vt[((size_t)bh * HD + d0 + dr) * KVLEN + kv0 + kq] = ov.u;
  }
}

// ---------------------------------------------------------------------------
// Flash attention v11 = v10 (swapped QK^T + in-reg P + deswizzle + KVBLK 64)
// + LDS DOUBLE-BUFFER: stage tile t+1 into buf[(t+1)&1] while computing
// tile t from buf[t&1] -> ONE barrier per tile instead of two (64 -> 32
// barrier drains per block). Race-free: buf[(t+1)&1]'s last readers were in
// iteration t-1, separated by that iteration's end barrier. Staging writes
// and prefetch globals now overlap the MFMA phase. LDS 35.8 -> 71.7KB,
// still 2 blocks/CU. v10 post-mortem: LDS pipe ~80-85% of wall (3.8K cy
// traffic + 1.5K conflict cy per 6.4K-cy tile-pair) with 64 full-drain
// barriers on top; occupancy stayed grid-limited at 19.6% (parallelism
// theories falsified 3x; chain/overhead-shortening is what wins).
// (Rounds 11-12 submissions died at the broker/container level — infra
// precedent from round 1; audited barrier/OOB/rotation invariants, sound.
// Resubmitting unchanged; if a 3rd failure, next round submits known-good
// v10 bytes to discriminate content vs infra.)
// ---------------------------------------------------------------------------
#define LSTR 136  // sK: d-stride = 128 + 8 pad (16B-aligned chunks)
#define VSTR 72   // sV: kv-stride = 64 + 8 pad
#define KSZ (64 * LSTR)
#define VSZ (128 * VSTR)

__global__ __launch_bounds__(256, 2) void attn(
    const u16* __restrict__ q, const u16* __restrict__ kfull,
    const u16* __restrict__ vt, const float* __restrict__ cosw,
    const float* __restrict__ sinw, const int* __restrict__ iscausal,
    u16* __restrict__ y)
{
  __shared__ u16 sK[2 * KSZ];   // K tiles [buf][kv][d]
  __shared__ u16 sV[2 * VSZ];   // V^T tiles [buf][d][kv]

  const int tid  = threadIdx.x;
  const int lane = tid & 63;
  const int w    = tid >> 6;
  const int quad = lane >> 4;
  const int mcol = lane & 15;
  // deswizzle: lin%8 = XCD. qt in bits [6:3] -> all qt of a bh share XCD.
  const int lin = blockIdx.x + 16 * blockIdx.y;  // 0..511
  const int qt  = (lin >> 3) & 15;
  const int bh  = (lin & 7) + 8 * (lin >> 7);
  const int b = bh >> 4, h = bh & 15;
  const int causal = *iscausal;
  const float SC = 0.08838834764831845f;  // 1/sqrt(128)

  // ---- Q fragments with fused rope, pre-scaled by SC (B-operand of
  // s = mfma(K, Q): lane holds Q[q=mcol][d=ks*32+quad*8+j]).
  bf16x8 qf[4];
  {
    const int trow = qt * 64 + w * 16 + mcol;
    const u16* qrow = q + ((size_t)b * TQ + trow) * D_MODEL + h * HD;
    const float* crow = cosw + trow * 64;
    const float* srow = sinw + trow * 64;
#pragma unroll
    for (int ks = 0; ks < 4; ++ks) {
      const int d0 = ks * 32 + quad * 8;
      U4 qv; qv.u = *(const u32x4*)(qrow + d0);
      f32x4 cv = *(const f32x4*)(crow + (d0 >> 1));
      f32x4 sv = *(const f32x4*)(srow + (d0 >> 1));
      bf16x8 dst;
#pragma unroll
      for (int p = 0; p < 4; ++p) {
        const float e = b2f(qv.s[2 * p]), o = b2f(qv.s[2 * p + 1]);
        const float re = fmaf(-o, sv[p], e * cv[p]);  // single-rounding combine
        const float im = fmaf( o, cv[p], e * sv[p]);
        dst[2 * p]     = (short)f2b(re * SC);
        dst[2 * p + 1] = (short)f2b(im * SC);
      }
      qf[ks] = dst;
    }
  }

  // staging coords:
  //   K: row rr = (tid>>4)+16j (0..63), elems sc8 = (tid&15)*8 of 128
  //   V: row dr = (tid>>3)+32j (0..127), elems vc8 = (tid&7)*8 of 64
  const int srow = tid >> 4;
  const int sc8  = (tid & 15) * 8;
  const int vrow_t = tid >> 3;
  const int vc8  = (tid & 7) * 8;
  const u16* kbase = kfull + (size_t)bh * KVLEN * HD;
  const u16* vbase = vt + (size_t)bh * HD * KVLEN;

  u32x4 kreg[4], vreg[4];
#define LOADT(KV0)                                                           \
  do {                                                                       \
    _Pragma("unroll") for (int j = 0; j < 4; ++j) {                          \
      const int rr = srow + 16 * j;                                          \
      const int dr = vrow_t + 32 * j;                                        \
      kreg[j] = *(const u32x4*)(kbase + ((size_t)(KV0) + rr) * HD + sc8);    \
      vreg[j] = *(const u32x4*)(vbase + (size_t)dr * KVLEN + (KV0) + vc8);   \
    }                                                                        \
  } while (0)

#define STAGE(BUF)                                                           \
  do {                                                                       \
    u16* dK = &sK[(BUF) * KSZ];                                              \
    u16* dV = &sV[(BUF) * VSZ];                                              \
    _Pragma("unroll") for (int j = 0; j < 4; ++j) {                          \
      const int rr = srow + 16 * j;                                          \
      const int dr = vrow_t + 32 * j;                                        \
      *(u32x4*)&dK[rr * LSTR + sc8] = kreg[j];                               \
      *(u32x4*)&dV[dr * VSTR + vc8] = vreg[j];                               \
    }                                                                        \
  } while (0)

  f32x4 oacc[8] = {};          // O[q=quad*4+r][d=nd*16+mcol] (C layout)
  float mrun = -3.0e38f;       // running max for q = mcol
  float lrun = 0.f;            // running denom for q = mcol

  // prologue: buf0 = tile 0 staged; regs = tile 1
  LOADT(0);
  STAGE(0);
  LOADT(64);
  __syncthreads();  // buf0 visible

  for (int t = 0; t < 32; ++t) {
    // stage next tile into the OTHER buffer (readers of it finished at the
    // barrier ending iteration t-1), then issue prefetch of tile t+2.
    if (t < 31) STAGE((t + 1) & 1);
    if (t < 30) LOADT((t + 2) * 64);

    const u16* cK = &sK[(t & 1) * KSZ];
    const u16* cV = &sV[(t & 1) * VSZ];
    const int kv0 = t * 64;

    // ---- S^T = K Q^T: s[nt][r] = S[q=mcol][kv = kv0 + nt*16 + quad*4 + r]
    f32x4 s[4] = {};
#pragma unroll
    for (int ks = 0; ks < 4; ++ks) {
      const int cc = ks * 4 + quad;
#pragma unroll
      for (int nt = 0; nt < 4; ++nt) {
        bf16x8 kf = *(const bf16x8*)&cK[(nt * 16 + mcol) * LSTR + cc * 8];
        s[nt] = __builtin_amdgcn_mfma_f32_16x16x32_bf16(kf, qf[ks], s[nt], 0, 0, 0);
      }
    }
    if (causal) {
      const int qi = qt * 64 + w * 16 + mcol;
#pragma unroll
      for (int nt = 0; nt < 4; ++nt)
#pragma unroll
        for (int r = 0; r < 4; ++r) {
          const int ki = kv0 + nt * 16 + quad * 4 + r;
          if (ki > qi + (KVLEN - TQ)) s[nt][r] = -1.0e30f;
        }
    }

    // ---- online softmax for q = mcol: in-lane over 16 + 2 shfl_xor
    float tm = -3.0e38f;
#pragma unroll
    for (int nt = 0; nt < 4; ++nt) {
      const float t01 = fmaxf(s[nt][0], s[nt][1]);
      const float t23 = fmaxf(s[nt][2], s[nt][3]);
      tm = fmaxf(tm, fmaxf(t01, t23));
    }
    tm = fmaxf(tm, __shfl_xor(tm, 16));
    tm = fmaxf(tm, __shfl_xor(tm, 32));
    const float mo = mrun;
    const float mn = fmaxf(mo, tm);
    mrun = mn;
    const float al = __expf(mo - mn);
    float rs = 0.f;
#pragma unroll
    for (int nt = 0; nt < 4; ++nt)
#pragma unroll
      for (int r = 0; r < 4; ++r) {
        const float p = __expf(s[nt][r] - mn);
        s[nt][r] = p;
        rs += p;
      }
    rs += __shfl_xor(rs, 16);
    rs += __shfl_xor(rs, 32);
    lrun = lrun * al + rs;

    // alpha for O rows: O row q = quad*4+r lives at source lane mcol=quad*4+r
    float al4[4];
#pragma unroll
    for (int r = 0; r < 4; ++r)
      al4[r] = __shfl(al, (lane & 48) + quad * 4 + r);
#pragma unroll
    for (int nd = 0; nd < 8; ++nd)
#pragma unroll
      for (int r = 0; r < 4; ++r) oacc[nd][r] *= al4[r];

    // ---- O += P V, P fully in registers (kv slot permutation as v9,
    // ks 0..1 over 64 kv). B-frag: two b64 reads per fragment.
#pragma unroll
    for (int ks = 0; ks < 2; ++ks) {
      U4 pa;
#pragma unroll
      for (int e = 0; e < 4; ++e) {
        pa.s[e]     = f2b(s[2 * ks][e]);
        pa.s[4 + e] = f2b(s[2 * ks + 1][e]);
      }
      const int kvlo = 32 * ks + 4 * quad;
#pragma unroll
      for (int nd = 0; nd < 8; ++nd) {
        const u16* vrow = &cV[(nd * 16 + mcol) * VSTR + kvlo];
        U4 vf;
        *(uint2*)&vf.s[0] = *(const uint2*)(vrow);
        *(uint2*)&vf.s[4] = *(const uint2*)(vrow + 16);
        oacc[nd] = __builtin_amdgcn_mfma_f32_16x16x32_bf16(
            *(const bf16x8*)&pa, *(const bf16x8*)&vf, oacc[nd], 0, 0, 0);
      }
    }

    __syncthreads();  // staging of t+1 visible; all waves leave tile t
  }
#undef STAGE
#undef LOADT

  // ---- epilogue: y[b, t, h*HD + d] = O / l (bf16); l crosses lanes like al
  float lq[4];
#pragma unroll
  for (int r = 0; r < 4; ++r)
    lq[r] = __shfl(lrun, (lane & 48) + quad * 4 + r);
#pragma unroll
  for (int r = 0; r < 4; ++r) {
    const int trow = qt * 64 + w * 16 + quad * 4 + r;
    const float inv = 1.0f / lq[r];
    u16* yr = y + ((size_t)b * TQ + trow) * D_MODEL + h * HD;
#pragma unroll
    for (int nd = 0; nd < 8; ++nd)
      yr[nd * 16 + mcol] = f2b(oacc[nd][r] * inv);
  }
}

// ---------------------------------------------------------------------------
extern "C" void kernel_launch(void* const* d_in, const int* in_sizes, int n_in,
                              void* d_out, int out_size, void* d_ws, size_t ws_size,
                              hipStream_t stream) {
  const float* x      = (const float*)d_in[0];
  const float* cosw   = (const float*)d_in[1];
  const float* sinw   = (const float*)d_in[2];
  const float* k_xl   = (const float*)d_in[3];
  const float* v_xl   = (const float*)d_in[4];
  const float* pos    = (const float*)d_in[5];
  const float* w_qkv  = (const float*)d_in[6];
  const float* w_proj = (const float*)d_in[7];
  const int* isc      = (const int*)d_in[8];
  float* out = (float*)d_out;

  // ws layout (58.7 MB, overlap-safe by stream order):
  //   qbuf  @ 0          8.4M  (gemm1 out, attn in)
  //   kbuf  @ 8388608    8.4M  (gemm1 out, prep_k in) -> y_ws after prep_k
  //   vbuf  @ 16777216   8.4M  (gemm1 out, transpose_v in)
  //   wqb   @ 25165824  25.2M  (cvt out, gemm1 in; dead after gemm1)
  //   kfull @ 25165824  16.8M  (prep_k out, attn in; overlays dead wqb)
  //   wpb   @ 25165824   8.4M  (cvt AFTER attn; overlays dead kfull)
  //   vt    @ 41943040  16.8M  (transpose_v out after gemm1; overlays wqb tail)
  //   xb    @ 50331648   8.4M  (cvt out, gemm1 in; overwritten by vt tail later)
  char* ws = (char*)d_ws;
  u16* qbuf  = (u16*)ws;
  u16* kbuf  = (u16*)(ws + (size_t)8388608);
  u16* vbuf  = (u16*)(ws + (size_t)16777216);
  u16* wqb   = (u16*)(ws + (size_t)25165824);
  u16* kfull = (u16*)(ws + (size_t)25165824);
  u16* wpb   = (u16*)(ws + (size_t)25165824);
  u16* vt    = (u16*)(ws + (size_t)41943040);
  u16* xb    = (u16*)(ws + (size_t)50331648);
  u16* y_ws  = kbuf;

  // 1) x fp32 -> bf16 (4,194,304 elems)
  cvt_bf16<<<2048, 256, 0, stream>>>(x, xb);
  // 2) w_qkv fp32 -> bf16 (12,582,912 elems)
  cvt_bf16<<<6144, 256, 0, stream>>>(w_qkv, wqb);

  // 3) q/k/v = x @ w_qkv^T  (all-bf16 async, C split bf16)
  dim3 g1(48, 16);
  gemm_bt<128, true><<<g1, 256, 0, stream>>>(xb, wqb, qbuf, kbuf, vbuf, 2048, 6144, 2048);

  // 4) kfull[b,h,kv,d]
  prep_k<<<4096, 256, 0, stream>>>(k_xl, pos, kbuf, cosw, sinw, kfull);

  // 5) vt[b,h,d,kv]
  dim3 gt(KVLEN / 64, HD / 64, BSZ * NHEADS);
  transpose_v<<<gt, 256, 0, stream>>>(v_xl, vbuf, vt);

  // 6) flash attention -> y bf16 (b,t,c); XCD-deswizzled block mapping
  dim3 ga(16, BSZ * NHEADS);
  attn<<<ga, 256, 0, stream>>>(qbuf, kfull, vt, cosw, sinw, isc, y_ws);

  // 7) w_proj fp32 -> bf16 (after attn: wpb overlays dead kfull)
  cvt_bf16<<<2048, 256, 0, stream>>>(w_proj, wpb);

  // 8) out = y @ w_proj^T  (all-bf16 async, 128x64 tiles -> 512 blocks, C fp32)
  dim3 g2(32, 16);
  gemm_bt<64, false><<<g2, 256, 0, stream>>>(y_ws, wpb, out, nullptr, nullptr, 2048, 2048, 2048);
}